// Round 1
// baseline (1053.061 us; speedup 1.0000x reference)
//
#include <hip/hip_runtime.h>
#include <cstddef>
#include <cmath>

#define NH   16
#define DH   64
#define SLEN 2048
#define DM   1024

// ---------------------------------------------------------------------------
// GEMM: C[M=4096, N=1024] = A[M,1024] @ W[1024,1024]^T + bias
// SCATTER=1: write C to [b, h, s, d] layout (b=m>>11, s=m&2047, h=n>>6, d=n&63)
// SCATTER=0: write C row-major [M, N]
// Block tile 128x128, 256 threads, per-thread 8x8 as 2x2 blocks of 4x4
// (row/col groups at offsets 0 and 64 -> conflict-free b128 LDS reads).
// ---------------------------------------------------------------------------
template<int SCATTER>
__global__ __launch_bounds__(256)
void gemm_bias(const float* __restrict__ A, const float* __restrict__ W,
               const float* __restrict__ bias, float* __restrict__ out)
{
    constexpr int K = DM;
    constexpr int N = DM;
    __shared__ float As[16][132];   // [k][m], stride 132 floats (16B aligned rows)
    __shared__ float Bs[16][132];   // [k][n]

    const int tid = threadIdx.x;
    const int tx  = tid & 15;        // -> N
    const int ty  = tid >> 4;        // -> M
    const int bm  = blockIdx.x * 128;
    const int bn  = blockIdx.y * 128;

    // staging loader: each thread brings one float4 from two rows of A and W
    const int lr = tid >> 2;          // 0..63
    const int lc = (tid & 3) << 2;    // 0,4,8,12
    const float* pA0 = A + (size_t)(bm + lr) * K + lc;
    const float* pA1 = pA0 + (size_t)64 * K;
    const float* pB0 = W + (size_t)(bn + lr) * K + lc;
    const float* pB1 = pB0 + (size_t)64 * K;

    float4 a0 = *(const float4*)pA0;
    float4 a1 = *(const float4*)pA1;
    float4 b0 = *(const float4*)pB0;
    float4 b1 = *(const float4*)pB1;

    float acc[8][8] = {};

    for (int k0 = 0; k0 < K; k0 += 16) {
        __syncthreads();   // previous iteration's LDS reads done
        As[lc+0][lr]    = a0.x; As[lc+1][lr]    = a0.y; As[lc+2][lr]    = a0.z; As[lc+3][lr]    = a0.w;
        As[lc+0][64+lr] = a1.x; As[lc+1][64+lr] = a1.y; As[lc+2][64+lr] = a1.z; As[lc+3][64+lr] = a1.w;
        Bs[lc+0][lr]    = b0.x; Bs[lc+1][lr]    = b0.y; Bs[lc+2][lr]    = b0.z; Bs[lc+3][lr]    = b0.w;
        Bs[lc+0][64+lr] = b1.x; Bs[lc+1][64+lr] = b1.y; Bs[lc+2][64+lr] = b1.z; Bs[lc+3][64+lr] = b1.w;
        __syncthreads();

        // prefetch next K-slab into registers; overlaps the compute below
        if (k0 + 16 < K) {
            a0 = *(const float4*)(pA0 + k0 + 16);
            a1 = *(const float4*)(pA1 + k0 + 16);
            b0 = *(const float4*)(pB0 + k0 + 16);
            b1 = *(const float4*)(pB1 + k0 + 16);
        }

        #pragma unroll
        for (int kk = 0; kk < 16; ++kk) {
            float4 av0 = *(const float4*)&As[kk][ty*4];
            float4 av1 = *(const float4*)&As[kk][64 + ty*4];
            float4 bv0 = *(const float4*)&Bs[kk][tx*4];
            float4 bv1 = *(const float4*)&Bs[kk][64 + tx*4];
            float ar[8] = {av0.x, av0.y, av0.z, av0.w, av1.x, av1.y, av1.z, av1.w};
            float br[8] = {bv0.x, bv0.y, bv0.z, bv0.w, bv1.x, bv1.y, bv1.z, bv1.w};
            #pragma unroll
            for (int i = 0; i < 8; ++i)
                #pragma unroll
                for (int j = 0; j < 8; ++j)
                    acc[i][j] = fmaf(ar[i], br[j], acc[i][j]);
        }
    }

    float4 bias0 = *(const float4*)&bias[bn + tx*4];
    float4 bias1 = *(const float4*)&bias[bn + 64 + tx*4];
    float bb[8] = {bias0.x, bias0.y, bias0.z, bias0.w, bias1.x, bias1.y, bias1.z, bias1.w};

    #pragma unroll
    for (int gr = 0; gr < 2; ++gr) {
        #pragma unroll
        for (int i = 0; i < 4; ++i) {
            const int m = bm + gr*64 + ty*4 + i;
            #pragma unroll
            for (int gc = 0; gc < 2; ++gc) {
                float4 v;
                v.x = acc[gr*4+i][gc*4+0] + bb[gc*4+0];
                v.y = acc[gr*4+i][gc*4+1] + bb[gc*4+1];
                v.z = acc[gr*4+i][gc*4+2] + bb[gc*4+2];
                v.w = acc[gr*4+i][gc*4+3] + bb[gc*4+3];
                if (SCATTER) {
                    const int bidx = m >> 11;
                    const int s    = m & 2047;
                    const int h    = (bn >> 6) + gc;
                    float* dst = out + ((((size_t)bidx*NH + h)*SLEN) + s)*DH + tx*4;
                    *(float4*)dst = v;
                } else {
                    *(float4*)&out[(size_t)m*N + bn + gc*64 + tx*4] = v;
                }
            }
        }
    }
}

// ---------------------------------------------------------------------------
// Flash attention, fp32: one block per (b, h, 64-row Q tile). 256 threads.
// Online softmax (running max/denominator). KV tiles of 64 rows.
// LDS: Qs/K transposed [d][row] (conflict-free b128 reads), V natural [row][d].
// K buffer is reused for the P tile after S is computed.
// ---------------------------------------------------------------------------
__global__ __launch_bounds__(256)
void flash_attn(const float* __restrict__ Qg, const float* __restrict__ Kg,
                const float* __restrict__ Vg, float* __restrict__ Og)
{
    __shared__ float Qs[64][68];   // [d][qrow]
    __shared__ float KP[64][68];   // K phase: [d][kvrow]; P phase: [qrow][kvcol]
    __shared__ float Vs[64][68];   // [kvrow][d]

    const int tid = threadIdx.x;
    const int tx  = tid & 15;      // -> kv col group (S) / d group (PV, output)
    const int ty  = tid >> 4;      // -> q row group
    const int q0  = blockIdx.x * 64;
    const int h   = blockIdx.y;
    const int b   = blockIdx.z;
    const size_t hb = (((size_t)b)*NH + h) * (size_t)SLEN * DH;

    // loader mapping: lane-major over rows -> conflict-free transposed LDS stores
    const int r  = tid & 63;
    const int cw = tid >> 6;       // 0..3 (wave id)

    #pragma unroll
    for (int it = 0; it < 4; ++it) {
        const int dc = (cw*4 + it)*4;
        float4 q4 = *(const float4*)&Qg[hb + (size_t)(q0 + r)*DH + dc];
        Qs[dc+0][r] = q4.x; Qs[dc+1][r] = q4.y; Qs[dc+2][r] = q4.z; Qs[dc+3][r] = q4.w;
    }

    float mx[4], li[4];
    float acc[4][4] = {};
    #pragma unroll
    for (int i = 0; i < 4; ++i) { mx[i] = -INFINITY; li[i] = 0.0f; }

    for (int t = 0; t < SLEN/64; ++t) {
        __syncthreads();   // previous PV reads done before overwriting KP/Vs
        #pragma unroll
        for (int it = 0; it < 4; ++it) {
            const int dc = (cw*4 + it)*4;
            const size_t base = hb + (size_t)(t*64 + r)*DH + dc;
            float4 k4 = *(const float4*)&Kg[base];
            float4 v4 = *(const float4*)&Vg[base];
            KP[dc+0][r] = k4.x; KP[dc+1][r] = k4.y; KP[dc+2][r] = k4.z; KP[dc+3][r] = k4.w;
            *(float4*)&Vs[r][dc] = v4;
        }
        __syncthreads();

        // S = (Q K^T) * 1/sqrt(64) — per thread a 4x4 patch
        float sv[4][4] = {};
        #pragma unroll
        for (int d = 0; d < 64; ++d) {
            float4 qv = *(const float4*)&Qs[d][ty*4];
            float4 kv = *(const float4*)&KP[d][tx*4];
            float qa[4] = {qv.x, qv.y, qv.z, qv.w};
            float ka[4] = {kv.x, kv.y, kv.z, kv.w};
            #pragma unroll
            for (int i = 0; i < 4; ++i)
                #pragma unroll
                for (int j = 0; j < 4; ++j)
                    sv[i][j] = fmaf(qa[i], ka[j], sv[i][j]);
        }

        // online softmax update (row groups of 16 lanes share a q-row)
        float p[4][4];
        #pragma unroll
        for (int i = 0; i < 4; ++i) {
            float rm = -INFINITY;
            #pragma unroll
            for (int j = 0; j < 4; ++j) { sv[i][j] *= 0.125f; rm = fmaxf(rm, sv[i][j]); }
            #pragma unroll
            for (int off = 1; off < 16; off <<= 1)
                rm = fmaxf(rm, __shfl_xor(rm, off));
            const float mn   = fmaxf(mx[i], rm);
            const float corr = __expf(mx[i] - mn);
            mx[i] = mn;
            float rs = 0.0f;
            #pragma unroll
            for (int j = 0; j < 4; ++j) { p[i][j] = __expf(sv[i][j] - mn); rs += p[i][j]; }
            #pragma unroll
            for (int off = 1; off < 16; off <<= 1)
                rs += __shfl_xor(rs, off);
            li[i] = li[i]*corr + rs;
            #pragma unroll
            for (int c = 0; c < 4; ++c) acc[i][c] *= corr;
        }

        __syncthreads();   // all lanes finished reading KP as K
        #pragma unroll
        for (int i = 0; i < 4; ++i)
            *(float4*)&KP[ty*4+i][tx*4] = make_float4(p[i][0], p[i][1], p[i][2], p[i][3]);
        __syncthreads();

        // O += P V  — per thread rows ty*4..+3, cols tx*4..+3
        #pragma unroll
        for (int j0 = 0; j0 < 64; j0 += 4) {
            float4 p0 = *(const float4*)&KP[ty*4+0][j0];
            float4 p1 = *(const float4*)&KP[ty*4+1][j0];
            float4 p2 = *(const float4*)&KP[ty*4+2][j0];
            float4 p3 = *(const float4*)&KP[ty*4+3][j0];
            float4 v0 = *(const float4*)&Vs[j0+0][tx*4];
            float4 v1 = *(const float4*)&Vs[j0+1][tx*4];
            float4 v2 = *(const float4*)&Vs[j0+2][tx*4];
            float4 v3 = *(const float4*)&Vs[j0+3][tx*4];
            float pr[4][4] = {{p0.x,p0.y,p0.z,p0.w},{p1.x,p1.y,p1.z,p1.w},
                              {p2.x,p2.y,p2.z,p2.w},{p3.x,p3.y,p3.z,p3.w}};
            float vr[4][4] = {{v0.x,v0.y,v0.z,v0.w},{v1.x,v1.y,v1.z,v1.w},
                              {v2.x,v2.y,v2.z,v2.w},{v3.x,v3.y,v3.z,v3.w}};
            #pragma unroll
            for (int i = 0; i < 4; ++i)
                #pragma unroll
                for (int jj = 0; jj < 4; ++jj)
                    #pragma unroll
                    for (int c = 0; c < 4; ++c)
                        acc[i][c] = fmaf(pr[i][jj], vr[jj][c], acc[i][c]);
        }
    }

    // finalize: divide by softmax denom, write [b, s, h*64+d]
    #pragma unroll
    for (int i = 0; i < 4; ++i) {
        const float inv = 1.0f / li[i];
        float4 v = make_float4(acc[i][0]*inv, acc[i][1]*inv, acc[i][2]*inv, acc[i][3]*inv);
        float* dst = Og + ((size_t)b*SLEN + q0 + ty*4 + i)*DM + h*DH + tx*4;
        *(float4*)dst = v;
    }
}

// ---------------------------------------------------------------------------
extern "C" void kernel_launch(void* const* d_in, const int* in_sizes, int n_in,
                              void* d_out, int out_size, void* d_ws, size_t ws_size,
                              hipStream_t stream)
{
    const float* x   = (const float*)d_in[0];
    const float* w_q = (const float*)d_in[1];
    const float* b_q = (const float*)d_in[2];
    const float* w_k = (const float*)d_in[3];
    const float* b_k = (const float*)d_in[4];
    const float* w_v = (const float*)d_in[5];
    const float* b_v = (const float*)d_in[6];
    const float* w_o = (const float*)d_in[7];
    const float* b_o = (const float*)d_in[8];
    float* out = (float*)d_out;

    // workspace layout (floats): Q | K | V in [b,h,s,d], then attn out [b,s,dm]
    float* ws = (float*)d_ws;
    const size_t QKV_ELEMS = (size_t)2 * NH * SLEN * DH;   // 4,194,304 (16 MB)
    float* Q  = ws;
    float* K  = ws +     QKV_ELEMS;
    float* V  = ws + 2 * QKV_ELEMS;
    float* AO = ws + 3 * QKV_ELEMS;

    dim3 gg(2*SLEN/128, DM/128);   // 32 x 8 = 256 blocks
    gemm_bias<1><<<gg, 256, 0, stream>>>(x, w_q, b_q, Q);
    gemm_bias<1><<<gg, 256, 0, stream>>>(x, w_k, b_k, K);
    gemm_bias<1><<<gg, 256, 0, stream>>>(x, w_v, b_v, V);

    dim3 ga(SLEN/64, NH, 2);       // 32 x 16 x 2 = 1024 blocks
    flash_attn<<<ga, 256, 0, stream>>>(Q, K, V, AO);

    gemm_bias<0><<<gg, 256, 0, stream>>>(AO, w_o, b_o, out);
}

// Round 2
// 790.802 us; speedup vs baseline: 1.3316x; 1.3316x over previous
//
#include <hip/hip_runtime.h>
#include <cstddef>
#include <cstdint>
#include <cmath>

#define NH   16
#define DH   64
#define SLEN 2048
#define DM   1024

typedef __bf16          bf16x8   __attribute__((ext_vector_type(8)));
typedef float           f32x4    __attribute__((ext_vector_type(4)));
typedef unsigned short  ushort8  __attribute__((ext_vector_type(8)));
typedef unsigned short  ushort4v __attribute__((ext_vector_type(4)));

// ---- bf16 helpers (RTNE) ---------------------------------------------------
__device__ __forceinline__ unsigned short f2bf(float x) {
    union { float f; unsigned u; } v; v.f = x;
    unsigned r = v.u + 0x7fffu + ((v.u >> 16) & 1u);
    return (unsigned short)(r >> 16);
}
__device__ __forceinline__ float bf2f(unsigned short h) {
    union { unsigned u; float f; } v; v.u = ((unsigned)h) << 16;
    return v.f;
}

__device__ __forceinline__ f32x4 mfma16(ushort8 a, ushort8 b, f32x4 c) {
    return __builtin_amdgcn_mfma_f32_16x16x32_bf16(
        __builtin_bit_cast(bf16x8, a), __builtin_bit_cast(bf16x8, b), c, 0, 0, 0);
}

// ---------------------------------------------------------------------------
// Convert x (4M floats) and the 4 weight matrices (1M floats each) into
// hi/lo bf16 pairs. One float4 chunk per thread; 2,097,152 chunks total.
// ---------------------------------------------------------------------------
__global__ __launch_bounds__(256)
void convert_hilo(const float* __restrict__ x,
                  const float* __restrict__ wq, const float* __restrict__ wk,
                  const float* __restrict__ wv, const float* __restrict__ wo,
                  unsigned short* __restrict__ xh, unsigned short* __restrict__ xl,
                  unsigned short* __restrict__ wh, unsigned short* __restrict__ wl)
{
    const unsigned c = blockIdx.x * 256 + threadIdx.x;   // chunk id (float4)
    const float* src;
    unsigned short *dh, *dl;
    size_t off;
    if (c < 1048576u) {                 // x: 1,048,576 chunks
        src = x; dh = xh; dl = xl; off = c;
    } else {
        unsigned t = c - 1048576u;
        unsigned wsel = t >> 18;        // each weight: 262,144 chunks
        off = t & 262143u;
        src  = (wsel == 0) ? wq : (wsel == 1) ? wk : (wsel == 2) ? wv : wo;
        dh = wh + ((size_t)wsel << 20);
        dl = wl + ((size_t)wsel << 20);
    }
    float4 v = *(const float4*)(src + off * 4);
    float a[4] = {v.x, v.y, v.z, v.w};
    ushort4v h, l;
    #pragma unroll
    for (int i = 0; i < 4; ++i) {
        unsigned short hi = f2bf(a[i]);
        h[i] = hi;
        l[i] = f2bf(a[i] - bf2f(hi));
    }
    *(ushort4v*)(dh + off * 4) = h;
    *(ushort4v*)(dl + off * 4) = l;
}

// ---------------------------------------------------------------------------
// Split-bf16 GEMM: C[M=4096,N=1024] = A @ W^T + bias, via 3x bf16 MFMA
// (Ahi*Whi + Ahi*Wlo + Alo*Whi), fp32 accumulation.
// 128x128 tile, BK=32, 256 threads = 4 waves (2x2), per wave 4x4 frags of
// mfma_f32_16x16x32_bf16. LDS rows padded to 40 bf16 (80 B) -> 2-way bank
// aliasing only (free). Register prefetch of next K-slab.
// SCATTER=1: write [b,h,s,d]; SCATTER=0: row-major [M,N].
// ---------------------------------------------------------------------------
template<int SCATTER>
__global__ __launch_bounds__(256, 1)
void gemm_split(const unsigned short* __restrict__ Ahi, const unsigned short* __restrict__ Alo,
                const unsigned short* __restrict__ Whi, const unsigned short* __restrict__ Wlo,
                const float* __restrict__ bias, float* __restrict__ out)
{
    constexpr int K = DM;
    __shared__ unsigned short sAh[128][40], sAl[128][40], sBh[128][40], sBl[128][40];

    const int tid  = threadIdx.x;
    const int bm   = blockIdx.x * 128;
    const int bn   = blockIdx.y * 128;
    const int wid  = tid >> 6;
    const int lane = tid & 63;
    const int wm   = (wid >> 1) * 64;
    const int wn   = (wid & 1) * 64;

    // staging mapping: chunk = (row, 8-elem col group); this thread owns
    // rows r0 and r0+64 at col c0 (16 B each) in every tile.
    const int r0 = tid >> 2;
    const int c0 = (tid & 3) * 8;

    const unsigned short* pAh0 = Ahi + (size_t)(bm + r0) * K + c0;
    const unsigned short* pAl0 = Alo + (size_t)(bm + r0) * K + c0;
    const unsigned short* pBh0 = Whi + (size_t)(bn + r0) * K + c0;
    const unsigned short* pBl0 = Wlo + (size_t)(bn + r0) * K + c0;
    const size_t rstep = (size_t)64 * K;

    ushort8 vah0, vah1, val0, val1, vbh0, vbh1, vbl0, vbl1;
    {
        vah0 = *(const ushort8*)(pAh0);         vah1 = *(const ushort8*)(pAh0 + rstep);
        val0 = *(const ushort8*)(pAl0);         val1 = *(const ushort8*)(pAl0 + rstep);
        vbh0 = *(const ushort8*)(pBh0);         vbh1 = *(const ushort8*)(pBh0 + rstep);
        vbl0 = *(const ushort8*)(pBl0);         vbl1 = *(const ushort8*)(pBl0 + rstep);
    }

    f32x4 acc[4][4];
    #pragma unroll
    for (int i = 0; i < 4; ++i)
        #pragma unroll
        for (int j = 0; j < 4; ++j)
            acc[i][j] = (f32x4)0.0f;

    const int fr = lane & 15;
    const int kq = (lane >> 4) * 8;

    for (int k0 = 0; k0 < K; k0 += 32) {
        __syncthreads();   // previous iteration's LDS reads complete
        *(ushort8*)&sAh[r0][c0]      = vah0;  *(ushort8*)&sAh[r0 + 64][c0] = vah1;
        *(ushort8*)&sAl[r0][c0]      = val0;  *(ushort8*)&sAl[r0 + 64][c0] = val1;
        *(ushort8*)&sBh[r0][c0]      = vbh0;  *(ushort8*)&sBh[r0 + 64][c0] = vbh1;
        *(ushort8*)&sBl[r0][c0]      = vbl0;  *(ushort8*)&sBl[r0 + 64][c0] = vbl1;
        __syncthreads();

        if (k0 + 32 < K) {
            const int kn = k0 + 32;
            vah0 = *(const ushort8*)(pAh0 + kn);         vah1 = *(const ushort8*)(pAh0 + rstep + kn);
            val0 = *(const ushort8*)(pAl0 + kn);         val1 = *(const ushort8*)(pAl0 + rstep + kn);
            vbh0 = *(const ushort8*)(pBh0 + kn);         vbh1 = *(const ushort8*)(pBh0 + rstep + kn);
            vbl0 = *(const ushort8*)(pBl0 + kn);         vbl1 = *(const ushort8*)(pBl0 + rstep + kn);
        }

        ushort8 afh[4], afl[4], bfh[4], bfl[4];
        #pragma unroll
        for (int i = 0; i < 4; ++i) {
            afh[i] = *(const ushort8*)&sAh[wm + i * 16 + fr][kq];
            afl[i] = *(const ushort8*)&sAl[wm + i * 16 + fr][kq];
            bfh[i] = *(const ushort8*)&sBh[wn + i * 16 + fr][kq];
            bfl[i] = *(const ushort8*)&sBl[wn + i * 16 + fr][kq];
        }

        #pragma unroll
        for (int i = 0; i < 4; ++i)
            #pragma unroll
            for (int j = 0; j < 4; ++j) {
                acc[i][j] = mfma16(afh[i], bfh[j], acc[i][j]);
                acc[i][j] = mfma16(afh[i], bfl[j], acc[i][j]);
                acc[i][j] = mfma16(afl[i], bfh[j], acc[i][j]);
            }
    }

    // epilogue: D layout col = lane&15, row = (lane>>4)*4 + q   [m89-verified]
    #pragma unroll
    for (int j = 0; j < 4; ++j) {
        const int n = bn + wn + j * 16 + fr;
        const float bs = bias[n];
        #pragma unroll
        for (int i = 0; i < 4; ++i) {
            #pragma unroll
            for (int q = 0; q < 4; ++q) {
                const int m = bm + wm + i * 16 + (lane >> 4) * 4 + q;
                const float v = acc[i][j][q] + bs;
                if (SCATTER) {
                    out[((((size_t)(m >> 11) * NH + (n >> 6)) * SLEN) + (m & 2047)) * DH + (n & 63)] = v;
                } else {
                    out[(size_t)m * DM + n] = v;
                }
            }
        }
    }
}

// ---------------------------------------------------------------------------
// Flash attention, fp32 (unchanged core). Epilogue now emits hi/lo bf16
// directly so the output projection can consume it without a conversion pass.
// ---------------------------------------------------------------------------
__global__ __launch_bounds__(256)
void flash_attn(const float* __restrict__ Qg, const float* __restrict__ Kg,
                const float* __restrict__ Vg,
                unsigned short* __restrict__ Ohi, unsigned short* __restrict__ Olo)
{
    __shared__ float Qs[64][68];
    __shared__ float KP[64][68];
    __shared__ float Vs[64][68];

    const int tid = threadIdx.x;
    const int tx  = tid & 15;
    const int ty  = tid >> 4;
    const int q0  = blockIdx.x * 64;
    const int h   = blockIdx.y;
    const int b   = blockIdx.z;
    const size_t hb = (((size_t)b) * NH + h) * (size_t)SLEN * DH;

    const int r  = tid & 63;
    const int cw = tid >> 6;

    #pragma unroll
    for (int it = 0; it < 4; ++it) {
        const int dc = (cw * 4 + it) * 4;
        float4 q4 = *(const float4*)&Qg[hb + (size_t)(q0 + r) * DH + dc];
        Qs[dc+0][r] = q4.x; Qs[dc+1][r] = q4.y; Qs[dc+2][r] = q4.z; Qs[dc+3][r] = q4.w;
    }

    float mx[4], li[4];
    float acc[4][4] = {};
    #pragma unroll
    for (int i = 0; i < 4; ++i) { mx[i] = -INFINITY; li[i] = 0.0f; }

    for (int t = 0; t < SLEN / 64; ++t) {
        __syncthreads();
        #pragma unroll
        for (int it = 0; it < 4; ++it) {
            const int dc = (cw * 4 + it) * 4;
            const size_t base = hb + (size_t)(t * 64 + r) * DH + dc;
            float4 k4 = *(const float4*)&Kg[base];
            float4 v4 = *(const float4*)&Vg[base];
            KP[dc+0][r] = k4.x; KP[dc+1][r] = k4.y; KP[dc+2][r] = k4.z; KP[dc+3][r] = k4.w;
            *(float4*)&Vs[r][dc] = v4;
        }
        __syncthreads();

        float sv[4][4] = {};
        #pragma unroll
        for (int d = 0; d < 64; ++d) {
            float4 qv = *(const float4*)&Qs[d][ty * 4];
            float4 kv = *(const float4*)&KP[d][tx * 4];
            float qa[4] = {qv.x, qv.y, qv.z, qv.w};
            float ka[4] = {kv.x, kv.y, kv.z, kv.w};
            #pragma unroll
            for (int i = 0; i < 4; ++i)
                #pragma unroll
                for (int j = 0; j < 4; ++j)
                    sv[i][j] = fmaf(qa[i], ka[j], sv[i][j]);
        }

        float p[4][4];
        #pragma unroll
        for (int i = 0; i < 4; ++i) {
            float rm = -INFINITY;
            #pragma unroll
            for (int j = 0; j < 4; ++j) { sv[i][j] *= 0.125f; rm = fmaxf(rm, sv[i][j]); }
            #pragma unroll
            for (int off = 1; off < 16; off <<= 1)
                rm = fmaxf(rm, __shfl_xor(rm, off));
            const float mn   = fmaxf(mx[i], rm);
            const float corr = __expf(mx[i] - mn);
            mx[i] = mn;
            float rs = 0.0f;
            #pragma unroll
            for (int j = 0; j < 4; ++j) { p[i][j] = __expf(sv[i][j] - mn); rs += p[i][j]; }
            #pragma unroll
            for (int off = 1; off < 16; off <<= 1)
                rs += __shfl_xor(rs, off);
            li[i] = li[i] * corr + rs;
            #pragma unroll
            for (int c = 0; c < 4; ++c) acc[i][c] *= corr;
        }

        __syncthreads();
        #pragma unroll
        for (int i = 0; i < 4; ++i)
            *(float4*)&KP[ty * 4 + i][tx * 4] = make_float4(p[i][0], p[i][1], p[i][2], p[i][3]);
        __syncthreads();

        #pragma unroll
        for (int j0 = 0; j0 < 64; j0 += 4) {
            float4 p0 = *(const float4*)&KP[ty*4+0][j0];
            float4 p1 = *(const float4*)&KP[ty*4+1][j0];
            float4 p2 = *(const float4*)&KP[ty*4+2][j0];
            float4 p3 = *(const float4*)&KP[ty*4+3][j0];
            float4 v0 = *(const float4*)&Vs[j0+0][tx*4];
            float4 v1 = *(const float4*)&Vs[j0+1][tx*4];
            float4 v2 = *(const float4*)&Vs[j0+2][tx*4];
            float4 v3 = *(const float4*)&Vs[j0+3][tx*4];
            float pr[4][4] = {{p0.x,p0.y,p0.z,p0.w},{p1.x,p1.y,p1.z,p1.w},
                              {p2.x,p2.y,p2.z,p2.w},{p3.x,p3.y,p3.z,p3.w}};
            float vr[4][4] = {{v0.x,v0.y,v0.z,v0.w},{v1.x,v1.y,v1.z,v1.w},
                              {v2.x,v2.y,v2.z,v2.w},{v3.x,v3.y,v3.z,v3.w}};
            #pragma unroll
            for (int i = 0; i < 4; ++i)
                #pragma unroll
                for (int jj = 0; jj < 4; ++jj)
                    #pragma unroll
                    for (int c = 0; c < 4; ++c)
                        acc[i][c] = fmaf(pr[i][jj], vr[jj][c], acc[i][c]);
        }
    }

    #pragma unroll
    for (int i = 0; i < 4; ++i) {
        const float inv = 1.0f / li[i];
        const size_t base = ((size_t)b * SLEN + q0 + ty * 4 + i) * DM + h * DH + tx * 4;
        ushort4v hv, lv;
        #pragma unroll
        for (int c = 0; c < 4; ++c) {
            const float v = acc[i][c] * inv;
            const unsigned short hh = f2bf(v);
            hv[c] = hh;
            lv[c] = f2bf(v - bf2f(hh));
        }
        *(ushort4v*)(Ohi + base) = hv;
        *(ushort4v*)(Olo + base) = lv;
    }
}

// ---------------------------------------------------------------------------
extern "C" void kernel_launch(void* const* d_in, const int* in_sizes, int n_in,
                              void* d_out, int out_size, void* d_ws, size_t ws_size,
                              hipStream_t stream)
{
    const float* x   = (const float*)d_in[0];
    const float* w_q = (const float*)d_in[1];
    const float* b_q = (const float*)d_in[2];
    const float* w_k = (const float*)d_in[3];
    const float* b_k = (const float*)d_in[4];
    const float* w_v = (const float*)d_in[5];
    const float* b_v = (const float*)d_in[6];
    const float* w_o = (const float*)d_in[7];
    const float* b_o = (const float*)d_in[8];
    float* out = (float*)d_out;

    // workspace (80 MB):
    //   [0,8)   MB: x_hi   (4M bf16)  -> reused as AO_hi after QKV GEMMs
    //   [8,16)  MB: x_lo              -> reused as AO_lo
    //   [16,24) MB: w_hi[4]  (4 x 1M bf16)
    //   [24,32) MB: w_lo[4]
    //   [32,48) MB: Q fp32   [b,h,s,d]
    //   [48,64) MB: K fp32
    //   [64,80) MB: V fp32
    char* w = (char*)d_ws;
    const size_t MB = 1024 * 1024;
    unsigned short* xh = (unsigned short*)(w);
    unsigned short* xl = (unsigned short*)(w + 8  * MB);
    unsigned short* wh = (unsigned short*)(w + 16 * MB);
    unsigned short* wl = (unsigned short*)(w + 24 * MB);
    float* Q  = (float*)(w + 32 * MB);
    float* Kt = (float*)(w + 48 * MB);
    float* V  = (float*)(w + 64 * MB);

    convert_hilo<<<8192, 256, 0, stream>>>(x, w_q, w_k, w_v, w_o, xh, xl, wh, wl);

    dim3 gg(2 * SLEN / 128, DM / 128);   // 32 x 8 = 256 blocks (1/CU)
    gemm_split<1><<<gg, 256, 0, stream>>>(xh, xl, wh + 0 * 1048576, wl + 0 * 1048576, b_q, Q);
    gemm_split<1><<<gg, 256, 0, stream>>>(xh, xl, wh + 1 * 1048576, wl + 1 * 1048576, b_k, Kt);
    gemm_split<1><<<gg, 256, 0, stream>>>(xh, xl, wh + 2 * 1048576, wl + 2 * 1048576, b_v, V);

    dim3 ga(SLEN / 64, NH, 2);           // 1024 blocks
    flash_attn<<<ga, 256, 0, stream>>>(Q, Kt, V, xh, xl);   // AO_hi/lo overwrite x_hi/lo

    gemm_split<0><<<gg, 256, 0, stream>>>(xh, xl, wh + 3 * 1048576, wl + 3 * 1048576, b_o, out);
}

// Round 4
// 489.695 us; speedup vs baseline: 2.1504x; 1.6149x over previous
//
#include <hip/hip_runtime.h>
#include <cstddef>
#include <cstdint>
#include <cmath>

#define NH   16
#define DH   64
#define SLEN 2048
#define DM   1024

typedef __bf16          bf16x8   __attribute__((ext_vector_type(8)));
typedef float           f32x4    __attribute__((ext_vector_type(4)));
typedef unsigned short  ushort8  __attribute__((ext_vector_type(8)));
typedef unsigned short  ushort4v __attribute__((ext_vector_type(4)));

// ---- bf16 helpers (RTNE) ---------------------------------------------------
__device__ __forceinline__ unsigned short f2bf(float x) {
    union { float f; unsigned u; } v; v.f = x;
    unsigned r = v.u + 0x7fffu + ((v.u >> 16) & 1u);
    return (unsigned short)(r >> 16);
}
__device__ __forceinline__ float bf2f(unsigned short h) {
    union { unsigned u; float f; } v; v.u = ((unsigned)h) << 16;
    return v.f;
}

__device__ __forceinline__ f32x4 mfma16(ushort8 a, ushort8 b, f32x4 c) {
    return __builtin_amdgcn_mfma_f32_16x16x32_bf16(
        __builtin_bit_cast(bf16x8, a), __builtin_bit_cast(bf16x8, b), c, 0, 0, 0);
}

// ---------------------------------------------------------------------------
// Convert x (4M floats) and the 4 weight matrices (1M floats each) into
// hi/lo bf16 pairs. One float4 chunk per thread; 2,097,152 chunks total.
// ---------------------------------------------------------------------------
__global__ __launch_bounds__(256)
void convert_hilo(const float* __restrict__ x,
                  const float* __restrict__ wq, const float* __restrict__ wk,
                  const float* __restrict__ wv, const float* __restrict__ wo,
                  unsigned short* __restrict__ xh, unsigned short* __restrict__ xl,
                  unsigned short* __restrict__ wh, unsigned short* __restrict__ wl)
{
    const unsigned c = blockIdx.x * 256 + threadIdx.x;
    const float* src;
    unsigned short *dh, *dl;
    size_t off;
    if (c < 1048576u) {
        src = x; dh = xh; dl = xl; off = c;
    } else {
        unsigned t = c - 1048576u;
        unsigned wsel = t >> 18;
        off = t & 262143u;
        src  = (wsel == 0) ? wq : (wsel == 1) ? wk : (wsel == 2) ? wv : wo;
        dh = wh + ((size_t)wsel << 20);
        dl = wl + ((size_t)wsel << 20);
    }
    float4 v = *(const float4*)(src + off * 4);
    float a[4] = {v.x, v.y, v.z, v.w};
    ushort4v h, l;
    #pragma unroll
    for (int i = 0; i < 4; ++i) {
        unsigned short hi = f2bf(a[i]);
        h[i] = hi;
        l[i] = f2bf(a[i] - bf2f(hi));
    }
    *(ushort4v*)(dh + off * 4) = h;
    *(ushort4v*)(dl + off * 4) = l;
}

// ---------------------------------------------------------------------------
// Split-bf16 GEMM: C[M=4096,N=1024] = A @ W^T + bias, via 3x bf16 MFMA.
// MODE 0: fp32 row-major [M,N]
// MODE 1: hi/lo bf16 scatter to [b,h,s,d]   (Q, K for attention)
// MODE 2: hi/lo bf16 scatter to [b,h,d,s]   (V transposed for attention)
// ---------------------------------------------------------------------------
template<int MODE>
__global__ __launch_bounds__(256, 1)
void gemm_split(const unsigned short* __restrict__ Ahi, const unsigned short* __restrict__ Alo,
                const unsigned short* __restrict__ Whi, const unsigned short* __restrict__ Wlo,
                const float* __restrict__ bias, float* __restrict__ outF,
                unsigned short* __restrict__ outH, unsigned short* __restrict__ outL)
{
    constexpr int K = DM;
    __shared__ unsigned short sAh[128][40], sAl[128][40], sBh[128][40], sBl[128][40];

    const int tid  = threadIdx.x;
    const int bm   = blockIdx.x * 128;
    const int bn   = blockIdx.y * 128;
    const int wid  = tid >> 6;
    const int lane = tid & 63;
    const int wm   = (wid >> 1) * 64;
    const int wn   = (wid & 1) * 64;

    const int r0 = tid >> 2;
    const int c0 = (tid & 3) * 8;

    const unsigned short* pAh0 = Ahi + (size_t)(bm + r0) * K + c0;
    const unsigned short* pAl0 = Alo + (size_t)(bm + r0) * K + c0;
    const unsigned short* pBh0 = Whi + (size_t)(bn + r0) * K + c0;
    const unsigned short* pBl0 = Wlo + (size_t)(bn + r0) * K + c0;
    const size_t rstep = (size_t)64 * K;

    ushort8 vah0 = *(const ushort8*)(pAh0), vah1 = *(const ushort8*)(pAh0 + rstep);
    ushort8 val0 = *(const ushort8*)(pAl0), val1 = *(const ushort8*)(pAl0 + rstep);
    ushort8 vbh0 = *(const ushort8*)(pBh0), vbh1 = *(const ushort8*)(pBh0 + rstep);
    ushort8 vbl0 = *(const ushort8*)(pBl0), vbl1 = *(const ushort8*)(pBl0 + rstep);

    f32x4 acc[4][4];
    #pragma unroll
    for (int i = 0; i < 4; ++i)
        #pragma unroll
        for (int j = 0; j < 4; ++j)
            acc[i][j] = (f32x4)0.0f;

    const int fr = lane & 15;
    const int kq = (lane >> 4) * 8;

    for (int k0 = 0; k0 < K; k0 += 32) {
        __syncthreads();
        *(ushort8*)&sAh[r0][c0]      = vah0;  *(ushort8*)&sAh[r0 + 64][c0] = vah1;
        *(ushort8*)&sAl[r0][c0]      = val0;  *(ushort8*)&sAl[r0 + 64][c0] = val1;
        *(ushort8*)&sBh[r0][c0]      = vbh0;  *(ushort8*)&sBh[r0 + 64][c0] = vbh1;
        *(ushort8*)&sBl[r0][c0]      = vbl0;  *(ushort8*)&sBl[r0 + 64][c0] = vbl1;
        __syncthreads();

        if (k0 + 32 < K) {
            const int kn = k0 + 32;
            vah0 = *(const ushort8*)(pAh0 + kn);  vah1 = *(const ushort8*)(pAh0 + rstep + kn);
            val0 = *(const ushort8*)(pAl0 + kn);  val1 = *(const ushort8*)(pAl0 + rstep + kn);
            vbh0 = *(const ushort8*)(pBh0 + kn);  vbh1 = *(const ushort8*)(pBh0 + rstep + kn);
            vbl0 = *(const ushort8*)(pBl0 + kn);  vbl1 = *(const ushort8*)(pBl0 + rstep + kn);
        }

        ushort8 afh[4], afl[4], bfh[4], bfl[4];
        #pragma unroll
        for (int i = 0; i < 4; ++i) {
            afh[i] = *(const ushort8*)&sAh[wm + i * 16 + fr][kq];
            afl[i] = *(const ushort8*)&sAl[wm + i * 16 + fr][kq];
            bfh[i] = *(const ushort8*)&sBh[wn + i * 16 + fr][kq];
            bfl[i] = *(const ushort8*)&sBl[wn + i * 16 + fr][kq];
        }

        #pragma unroll
        for (int i = 0; i < 4; ++i)
            #pragma unroll
            for (int j = 0; j < 4; ++j) {
                acc[i][j] = mfma16(afh[i], bfh[j], acc[i][j]);
                acc[i][j] = mfma16(afh[i], bfl[j], acc[i][j]);
                acc[i][j] = mfma16(afl[i], bfh[j], acc[i][j]);
            }
    }

    // epilogue: D layout col = lane&15, row = (lane>>4)*4 + q
    #pragma unroll
    for (int j = 0; j < 4; ++j) {
        const int n = bn + wn + j * 16 + fr;
        const float bs = bias[n];
        #pragma unroll
        for (int i = 0; i < 4; ++i) {
            #pragma unroll
            for (int q = 0; q < 4; ++q) {
                const int m = bm + wm + i * 16 + (lane >> 4) * 4 + q;
                const float v = acc[i][j][q] + bs;
                if (MODE == 0) {
                    outF[(size_t)m * DM + n] = v;
                } else {
                    const int bb = m >> 11, s = m & 2047, hh = n >> 6, dd = n & 63;
                    size_t idx;
                    if (MODE == 1) idx = ((((size_t)bb * NH + hh) * SLEN) + s) * DH + dd;
                    else           idx = ((((size_t)bb * NH + hh) * DH) + dd) * SLEN + s;
                    const unsigned short vh = f2bf(v);
                    outH[idx] = vh;
                    outL[idx] = f2bf(v - bf2f(vh));
                }
            }
        }
    }
}

// ---------------------------------------------------------------------------
// Flash attention via split-bf16 MFMA. One block per (b, h, 64-row q tile),
// 4 waves x 16 q rows. K tile natural [kv][d], Vt tile [d][kv], both hi/lo
// bf16 in LDS ([64][72] rows -> uniform bank spread for the frag reads).
// P goes through a wave-private fp32 LDS tile (in-order DS pipe, no barrier).
// ---------------------------------------------------------------------------
__global__ __launch_bounds__(256)
void flash_attn_mfma(const unsigned short* __restrict__ Qh, const unsigned short* __restrict__ Ql,
                     const unsigned short* __restrict__ Kh, const unsigned short* __restrict__ Kl,
                     const unsigned short* __restrict__ Vth, const unsigned short* __restrict__ Vtl,
                     unsigned short* __restrict__ Ohi, unsigned short* __restrict__ Olo)
{
    __shared__ unsigned short sKh[64][72], sKl[64][72], sVh[64][72], sVl[64][72];
    __shared__ float sP[4][16][68];

    const int tid  = threadIdx.x;
    const int wid  = tid >> 6;
    const int lane = tid & 63;
    const int fr   = lane & 15;
    const int g    = lane >> 4;
    const int kq   = g * 8;
    const int q0   = blockIdx.x * 64;
    const int h    = blockIdx.y;
    const int b    = blockIdx.z;
    const size_t hb = (((size_t)b) * NH + h) * (size_t)SLEN * DH;

    // staging mapping: 4 threads per row, 32B each
    const int r0 = tid >> 2;
    const int cq = (tid & 3) * 16;

    // Q fragments: row fr of this wave's 16-row tile, d = ks*32 + kq..+7
    ushort8 qh[2], ql[2];
    {
        const size_t qbase = hb + (size_t)(q0 + wid * 16 + fr) * DH;
        qh[0] = *(const ushort8*)&Qh[qbase + kq];
        qh[1] = *(const ushort8*)&Qh[qbase + 32 + kq];
        ql[0] = *(const ushort8*)&Ql[qbase + kq];
        ql[1] = *(const ushort8*)&Ql[qbase + 32 + kq];
    }

    float mx[4], li[4];
    f32x4 acc[4];                    // [d-frag]; lane r -> q row g*4+r
    #pragma unroll
    for (int r = 0; r < 4; ++r) { mx[r] = -INFINITY; li[r] = 0.0f; }
    #pragma unroll
    for (int j = 0; j < 4; ++j) acc[j] = (f32x4)0.0f;

    for (int t = 0; t < SLEN / 64; ++t) {
        __syncthreads();   // previous tile's K/Vt reads complete
        {
            const size_t kbase = hb + (size_t)(t * 64 + r0) * DH + cq;
            *(ushort8*)&sKh[r0][cq]     = *(const ushort8*)&Kh[kbase];
            *(ushort8*)&sKh[r0][cq + 8] = *(const ushort8*)&Kh[kbase + 8];
            *(ushort8*)&sKl[r0][cq]     = *(const ushort8*)&Kl[kbase];
            *(ushort8*)&sKl[r0][cq + 8] = *(const ushort8*)&Kl[kbase + 8];
            const size_t vbase = hb + (size_t)r0 * SLEN + t * 64 + cq;
            *(ushort8*)&sVh[r0][cq]     = *(const ushort8*)&Vth[vbase];
            *(ushort8*)&sVh[r0][cq + 8] = *(const ushort8*)&Vth[vbase + 8];
            *(ushort8*)&sVl[r0][cq]     = *(const ushort8*)&Vtl[vbase];
            *(ushort8*)&sVl[r0][cq + 8] = *(const ushort8*)&Vtl[vbase + 8];
        }
        __syncthreads();

        // S = Q K^T : per wave 16 q rows x 64 kv cols (4 col-frags)
        f32x4 s[4];
        #pragma unroll
        for (int j = 0; j < 4; ++j) s[j] = (f32x4)0.0f;
        #pragma unroll
        for (int j = 0; j < 4; ++j) {
            #pragma unroll
            for (int ks = 0; ks < 2; ++ks) {
                ushort8 kfh = *(const ushort8*)&sKh[j * 16 + fr][ks * 32 + kq];
                ushort8 kfl = *(const ushort8*)&sKl[j * 16 + fr][ks * 32 + kq];
                s[j] = mfma16(qh[ks], kfh, s[j]);
                s[j] = mfma16(qh[ks], kfl, s[j]);
                s[j] = mfma16(ql[ks], kfh, s[j]);
            }
        }

        // online softmax: lane's rows are g*4+r, cols j*16+fr
        float p[4][4];   // [r][j]
        #pragma unroll
        for (int r = 0; r < 4; ++r) {
            float sc[4];
            float rm = -INFINITY;
            #pragma unroll
            for (int j = 0; j < 4; ++j) { sc[j] = s[j][r] * 0.125f; rm = fmaxf(rm, sc[j]); }
            #pragma unroll
            for (int off = 1; off < 16; off <<= 1)
                rm = fmaxf(rm, __shfl_xor(rm, off));
            const float mn   = fmaxf(mx[r], rm);
            const float corr = __expf(mx[r] - mn);
            mx[r] = mn;
            float rs = 0.0f;
            #pragma unroll
            for (int j = 0; j < 4; ++j) { p[r][j] = __expf(sc[j] - mn); rs += p[r][j]; }
            #pragma unroll
            for (int off = 1; off < 16; off <<= 1)
                rs += __shfl_xor(rs, off);
            li[r] = li[r] * corr + rs;
            #pragma unroll
            for (int j = 0; j < 4; ++j) acc[j][r] *= corr;
        }

        // P -> wave-private LDS (rows g*4+r, cols j*16+fr); in-wave DS order
        #pragma unroll
        for (int r = 0; r < 4; ++r)
            #pragma unroll
            for (int j = 0; j < 4; ++j)
                sP[wid][g * 4 + r][j * 16 + fr] = p[r][j];

        // O += P V : A = P (row fr), B = Vt (col fr)
        #pragma unroll
        for (int ks = 0; ks < 2; ++ks) {
            float4 pa = *(const float4*)&sP[wid][fr][ks * 32 + kq];
            float4 pb = *(const float4*)&sP[wid][fr][ks * 32 + kq + 4];
            float pe[8] = {pa.x, pa.y, pa.z, pa.w, pb.x, pb.y, pb.z, pb.w};
            ushort8 ph, pl;
            #pragma unroll
            for (int e = 0; e < 8; ++e) {
                const unsigned short hh = f2bf(pe[e]);
                ph[e] = hh;
                pl[e] = f2bf(pe[e] - bf2f(hh));
            }
            #pragma unroll
            for (int j = 0; j < 4; ++j) {
                ushort8 vfh = *(const ushort8*)&sVh[j * 16 + fr][ks * 32 + kq];
                ushort8 vfl = *(const ushort8*)&sVl[j * 16 + fr][ks * 32 + kq];
                acc[j] = mfma16(ph, vfh, acc[j]);
                acc[j] = mfma16(ph, vfl, acc[j]);
                acc[j] = mfma16(pl, vfh, acc[j]);
            }
        }
    }

    // epilogue: q = q0 + wid*16 + g*4 + r, d = j*16 + fr; write hi/lo bf16
    #pragma unroll
    for (int r = 0; r < 4; ++r) {
        const float inv = 1.0f / li[r];
        const int q = q0 + wid * 16 + g * 4 + r;
        const size_t base = ((size_t)b * SLEN + q) * DM + h * DH;
        #pragma unroll
        for (int j = 0; j < 4; ++j) {
            const float v = acc[j][r] * inv;
            const unsigned short hh = f2bf(v);
            Ohi[base + j * 16 + fr] = hh;
            Olo[base + j * 16 + fr] = f2bf(v - bf2f(hh));
        }
    }
}

// ---------------------------------------------------------------------------
extern "C" void kernel_launch(void* const* d_in, const int* in_sizes, int n_in,
                              void* d_out, int out_size, void* d_ws, size_t ws_size,
                              hipStream_t stream)
{
    const float* x   = (const float*)d_in[0];
    const float* w_q = (const float*)d_in[1];
    const float* b_q = (const float*)d_in[2];
    const float* w_k = (const float*)d_in[3];
    const float* b_k = (const float*)d_in[4];
    const float* w_v = (const float*)d_in[5];
    const float* b_v = (const float*)d_in[6];
    const float* w_o = (const float*)d_in[7];
    const float* b_o = (const float*)d_in[8];
    float* out = (float*)d_out;

    // workspace (80 MB), all bf16:
    //   [0,8)   xh  (-> AO_hi after QKV)     [8,16)  xl (-> AO_lo)
    //   [16,24) wh[4]                        [24,32) wl[4]
    //   [32,40) Qh   [40,48) Ql   [48,56) Kh   [56,64) Kl
    //   [64,72) Vth  [72,80) Vtl
    char* w = (char*)d_ws;
    const size_t MB = 1024 * 1024;
    unsigned short* xh  = (unsigned short*)(w);
    unsigned short* xl  = (unsigned short*)(w + 8  * MB);
    unsigned short* wh  = (unsigned short*)(w + 16 * MB);
    unsigned short* wl  = (unsigned short*)(w + 24 * MB);
    unsigned short* Qh  = (unsigned short*)(w + 32 * MB);
    unsigned short* Ql  = (unsigned short*)(w + 40 * MB);
    unsigned short* Kh  = (unsigned short*)(w + 48 * MB);
    unsigned short* Kl  = (unsigned short*)(w + 56 * MB);
    unsigned short* Vth = (unsigned short*)(w + 64 * MB);
    unsigned short* Vtl = (unsigned short*)(w + 72 * MB);

    convert_hilo<<<8192, 256, 0, stream>>>(x, w_q, w_k, w_v, w_o, xh, xl, wh, wl);

    dim3 gg(2 * SLEN / 128, DM / 128);
    gemm_split<1><<<gg, 256, 0, stream>>>(xh, xl, wh + 0 * 1048576, wl + 0 * 1048576, b_q, nullptr, Qh, Ql);
    gemm_split<1><<<gg, 256, 0, stream>>>(xh, xl, wh + 1 * 1048576, wl + 1 * 1048576, b_k, nullptr, Kh, Kl);
    gemm_split<2><<<gg, 256, 0, stream>>>(xh, xl, wh + 2 * 1048576, wl + 2 * 1048576, b_v, nullptr, Vth, Vtl);

    dim3 ga(SLEN / 64, NH, 2);
    flash_attn_mfma<<<ga, 256, 0, stream>>>(Qh, Ql, Kh, Kl, Vth, Vtl, xh, xl);

    gemm_split<0><<<gg, 256, 0, stream>>>(xh, xl, wh + 3 * 1048576, wl + 3 * 1048576, b_o, out, nullptr, nullptr);
}

// Round 11
// 464.900 us; speedup vs baseline: 2.2651x; 1.0533x over previous
//
#include <hip/hip_runtime.h>
#include <cstddef>
#include <cstdint>
#include <cmath>

#define NH   16
#define DH   64
#define SLEN 2048
#define DM   1024

typedef __bf16          bf16x8   __attribute__((ext_vector_type(8)));
typedef float           f32x4    __attribute__((ext_vector_type(4)));
typedef unsigned short  ushort8  __attribute__((ext_vector_type(8)));
typedef unsigned short  ushort4v __attribute__((ext_vector_type(4)));

// ---- bf16 helpers (RTNE) ---------------------------------------------------
__device__ __forceinline__ unsigned short f2bf(float x) {
    union { float f; unsigned u; } v; v.f = x;
    unsigned r = v.u + 0x7fffu + ((v.u >> 16) & 1u);
    return (unsigned short)(r >> 16);
}
__device__ __forceinline__ float bf2f(unsigned short h) {
    union { unsigned u; float f; } v; v.u = ((unsigned)h) << 16;
    return v.f;
}

__device__ __forceinline__ f32x4 mfma16(ushort8 a, ushort8 b, f32x4 c) {
    return __builtin_amdgcn_mfma_f32_16x16x32_bf16(
        __builtin_bit_cast(bf16x8, a), __builtin_bit_cast(bf16x8, b), c, 0, 0, 0);
}

// ---------------------------------------------------------------------------
// Convert x (4M floats) and the 4 weight matrices (1M floats each) into
// hi/lo bf16 pairs.
// ---------------------------------------------------------------------------
__global__ __launch_bounds__(256)
void convert_hilo(const float* __restrict__ x,
                  const float* __restrict__ wq, const float* __restrict__ wk,
                  const float* __restrict__ wv, const float* __restrict__ wo,
                  unsigned short* __restrict__ xh, unsigned short* __restrict__ xl,
                  unsigned short* __restrict__ wh, unsigned short* __restrict__ wl)
{
    const unsigned c = blockIdx.x * 256 + threadIdx.x;
    const float* src;
    unsigned short *dh, *dl;
    size_t off;
    if (c < 1048576u) {
        src = x; dh = xh; dl = xl; off = c;
    } else {
        unsigned t = c - 1048576u;
        unsigned wsel = t >> 18;
        off = t & 262143u;
        src  = (wsel == 0) ? wq : (wsel == 1) ? wk : (wsel == 2) ? wv : wo;
        dh = wh + ((size_t)wsel << 20);
        dl = wl + ((size_t)wsel << 20);
    }
    float4 v = *(const float4*)(src + off * 4);
    float a[4] = {v.x, v.y, v.z, v.w};
    ushort4v h, l;
    #pragma unroll
    for (int i = 0; i < 4; ++i) {
        unsigned short hi = f2bf(a[i]);
        h[i] = hi;
        l[i] = f2bf(a[i] - bf2f(hi));
    }
    *(ushort4v*)(dh + off * 4) = h;
    *(ushort4v*)(dl + off * 4) = l;
}

// ---------------------------------------------------------------------------
// Split-bf16 GEMM: C[M=4096,N=1024] = (A @ W^T + bias) * scale, 3x bf16 MFMA.
// MODE 0: fp32 row-major [M,N]
// MODE 1: hi/lo bf16 scatter to [b,h,s,d]   (Q with scale=1/8, K)
// MODE 2: hi/lo bf16 to [b,h,d,s] via LDS-transposed coalesced epilogue (V)
// ---------------------------------------------------------------------------
template<int MODE>
__global__ __launch_bounds__(256, 1)
void gemm_split(const unsigned short* __restrict__ Ahi, const unsigned short* __restrict__ Alo,
                const unsigned short* __restrict__ Whi, const unsigned short* __restrict__ Wlo,
                const float* __restrict__ bias, const float scale, float* __restrict__ outF,
                unsigned short* __restrict__ outH, unsigned short* __restrict__ outL)
{
    constexpr int K = DM;
    __shared__ __align__(16) char smem[40960];
    auto sAh = (unsigned short(*)[40])(smem);
    auto sAl = (unsigned short(*)[40])(smem + 10240);
    auto sBh = (unsigned short(*)[40])(smem + 20480);
    auto sBl = (unsigned short(*)[40])(smem + 30720);

    const int tid  = threadIdx.x;
    const int bm   = blockIdx.x * 128;
    const int bn   = blockIdx.y * 128;
    const int wid  = tid >> 6;
    const int lane = tid & 63;
    const int wm   = (wid >> 1) * 64;
    const int wn   = (wid & 1) * 64;

    const int r0 = tid >> 2;
    const int c0 = (tid & 3) * 8;

    const unsigned short* pAh0 = Ahi + (size_t)(bm + r0) * K + c0;
    const unsigned short* pAl0 = Alo + (size_t)(bm + r0) * K + c0;
    const unsigned short* pBh0 = Whi + (size_t)(bn + r0) * K + c0;
    const unsigned short* pBl0 = Wlo + (size_t)(bn + r0) * K + c0;
    const size_t rstep = (size_t)64 * K;

    ushort8 vah0 = *(const ushort8*)(pAh0), vah1 = *(const ushort8*)(pAh0 + rstep);
    ushort8 val0 = *(const ushort8*)(pAl0), val1 = *(const ushort8*)(pAl0 + rstep);
    ushort8 vbh0 = *(const ushort8*)(pBh0), vbh1 = *(const ushort8*)(pBh0 + rstep);
    ushort8 vbl0 = *(const ushort8*)(pBl0), vbl1 = *(const ushort8*)(pBl0 + rstep);

    f32x4 acc[4][4];
    #pragma unroll
    for (int i = 0; i < 4; ++i)
        #pragma unroll
        for (int j = 0; j < 4; ++j)
            acc[i][j] = (f32x4)0.0f;

    const int fr = lane & 15;
    const int kq = (lane >> 4) * 8;

    for (int k0 = 0; k0 < K; k0 += 32) {
        __syncthreads();
        *(ushort8*)&sAh[r0][c0]      = vah0;  *(ushort8*)&sAh[r0 + 64][c0] = vah1;
        *(ushort8*)&sAl[r0][c0]      = val0;  *(ushort8*)&sAl[r0 + 64][c0] = val1;
        *(ushort8*)&sBh[r0][c0]      = vbh0;  *(ushort8*)&sBh[r0 + 64][c0] = vbh1;
        *(ushort8*)&sBl[r0][c0]      = vbl0;  *(ushort8*)&sBl[r0 + 64][c0] = vbl1;
        __syncthreads();

        if (k0 + 32 < K) {
            const int kn = k0 + 32;
            vah0 = *(const ushort8*)(pAh0 + kn);  vah1 = *(const ushort8*)(pAh0 + rstep + kn);
            val0 = *(const ushort8*)(pAl0 + kn);  val1 = *(const ushort8*)(pAl0 + rstep + kn);
            vbh0 = *(const ushort8*)(pBh0 + kn);  vbh1 = *(const ushort8*)(pBh0 + rstep + kn);
            vbl0 = *(const ushort8*)(pBl0 + kn);  vbl1 = *(const ushort8*)(pBl0 + rstep + kn);
        }

        ushort8 afh[4], afl[4], bfh[4], bfl[4];
        #pragma unroll
        for (int i = 0; i < 4; ++i) {
            afh[i] = *(const ushort8*)&sAh[wm + i * 16 + fr][kq];
            afl[i] = *(const ushort8*)&sAl[wm + i * 16 + fr][kq];
            bfh[i] = *(const ushort8*)&sBh[wn + i * 16 + fr][kq];
            bfl[i] = *(const ushort8*)&sBl[wn + i * 16 + fr][kq];
        }

        #pragma unroll
        for (int i = 0; i < 4; ++i)
            #pragma unroll
            for (int j = 0; j < 4; ++j) {
                acc[i][j] = mfma16(afh[i], bfh[j], acc[i][j]);
                acc[i][j] = mfma16(afh[i], bfl[j], acc[i][j]);
                acc[i][j] = mfma16(afl[i], bfh[j], acc[i][j]);
            }
    }

    if (MODE == 2) {
        // Coalesced V^T epilogue: stage 64(n) x 128(m) f32 halves through LDS,
        // then store rows with s contiguous (16B hi/lo stores).
        float (*sT)[132] = (float(*)[132])smem;
        const int bb2 = bm >> 11;       // batch
        const int sm  = bm & 2047;      // seq offset within batch (BUGFIX r10)
        #pragma unroll
        for (int ph = 0; ph < 2; ++ph) {
            __syncthreads();
            if ((wid & 1) == ph) {
                #pragma unroll
                for (int j = 0; j < 4; ++j) {
                    const float bs = bias[bn + ph * 64 + j * 16 + fr];
                    #pragma unroll
                    for (int i = 0; i < 4; ++i) {
                        float4 v4;
                        v4.x = acc[i][j][0] + bs;
                        v4.y = acc[i][j][1] + bs;
                        v4.z = acc[i][j][2] + bs;
                        v4.w = acc[i][j][3] + bs;
                        *(float4*)&sT[j * 16 + fr][wm + i * 16 + (lane >> 4) * 4] = v4;
                    }
                }
            }
            __syncthreads();
            #pragma unroll
            for (int half = 0; half < 2; ++half) {
                const int r  = (tid >> 3) + half * 32;
                const int cc = (tid & 7) * 16;
                const int n  = bn + ph * 64 + r;
                const size_t gb = ((((size_t)bb2 * NH + (n >> 6)) * DH) + (n & 63)) * SLEN + sm + cc;
                #pragma unroll
                for (int u = 0; u < 2; ++u) {
                    float4 f0 = *(const float4*)&sT[r][cc + u * 8];
                    float4 f1 = *(const float4*)&sT[r][cc + u * 8 + 4];
                    float fe[8] = {f0.x, f0.y, f0.z, f0.w, f1.x, f1.y, f1.z, f1.w};
                    ushort8 hv, lv;
                    #pragma unroll
                    for (int e = 0; e < 8; ++e) {
                        const unsigned short vh = f2bf(fe[e]);
                        hv[e] = vh;
                        lv[e] = f2bf(fe[e] - bf2f(vh));
                    }
                    *(ushort8*)(outH + gb + u * 8) = hv;
                    *(ushort8*)(outL + gb + u * 8) = lv;
                }
            }
        }
        return;
    }

    // MODE 0 / MODE 1 epilogue: D layout col = lane&15, row = (lane>>4)*4 + q
    #pragma unroll
    for (int j = 0; j < 4; ++j) {
        const int n = bn + wn + j * 16 + fr;
        const float bs = bias[n];
        #pragma unroll
        for (int i = 0; i < 4; ++i) {
            #pragma unroll
            for (int q = 0; q < 4; ++q) {
                const int m = bm + wm + i * 16 + (lane >> 4) * 4 + q;
                const float v = (acc[i][j][q] + bs) * scale;
                if (MODE == 0) {
                    outF[(size_t)m * DM + n] = v;
                } else {
                    const int bb = m >> 11, s = m & 2047, hh = n >> 6, dd = n & 63;
                    const size_t idx = ((((size_t)bb * NH + hh) * SLEN) + s) * DH + dd;
                    const unsigned short vh = f2bf(v);
                    outH[idx] = vh;
                    outL[idx] = f2bf(v - bf2f(vh));
                }
            }
        }
    }
}

// ---------------------------------------------------------------------------
// Flash attention via split-bf16 MFMA, KVBLK=32.
// One block per (b, h, 64-row q tile), 4 waves x 16 q rows.
// LDS 28KB -> 5 blocks/CU. K tile [32 kv][64 d], Vt tile [64 d][32 kv],
// hi/lo bf16; P via wave-private fp32 LDS (in-order DS pipe, no barrier).
// 1/sqrt(64) pre-folded into Q by the Q projection (scale=0.125).
// ---------------------------------------------------------------------------
__global__ __launch_bounds__(256, 5)
void flash_attn_mfma(const unsigned short* __restrict__ Qh, const unsigned short* __restrict__ Ql,
                     const unsigned short* __restrict__ Kh, const unsigned short* __restrict__ Kl,
                     const unsigned short* __restrict__ Vth, const unsigned short* __restrict__ Vtl,
                     unsigned short* __restrict__ Ohi, unsigned short* __restrict__ Olo)
{
    __shared__ unsigned short sKh[32][72], sKl[32][72];   // [kv][d]   144B rows
    __shared__ unsigned short sVh[64][40], sVl[64][40];   // [d][kv]    80B rows
    __shared__ float sP[4][16][36];                       // per wave [q][kv]

    const int tid  = threadIdx.x;
    const int wid  = tid >> 6;
    const int lane = tid & 63;
    const int fr   = lane & 15;
    const int g    = lane >> 4;
    const int kq   = g * 8;
    const int q0   = blockIdx.x * 64;
    const int h    = blockIdx.y;
    const int b    = blockIdx.z;
    const size_t hb = (((size_t)b) * NH + h) * (size_t)SLEN * DH;

    // staging mappings
    const int kr = tid & 31, kc = (tid >> 5) * 8;   // K: [32 kv][64 d]
    const int vr = tid >> 2, vc = (tid & 3) * 8;    // Vt: [64 d][32 kv]

    // Q fragments: row fr of this wave's 16-row tile
    ushort8 qh[2], ql[2];
    {
        const size_t qbase = hb + (size_t)(q0 + wid * 16 + fr) * DH;
        qh[0] = *(const ushort8*)&Qh[qbase + kq];
        qh[1] = *(const ushort8*)&Qh[qbase + 32 + kq];
        ql[0] = *(const ushort8*)&Ql[qbase + kq];
        ql[1] = *(const ushort8*)&Ql[qbase + 32 + kq];
    }

    float mx[4], li[4];
    f32x4 acc[4];                    // [d-frag]; reg r -> q row g*4+r
    #pragma unroll
    for (int r = 0; r < 4; ++r) { mx[r] = -INFINITY; li[r] = 0.0f; }
    #pragma unroll
    for (int j = 0; j < 4; ++j) acc[j] = (f32x4)0.0f;

    for (int t = 0; t < SLEN / 32; ++t) {
        __syncthreads();   // previous tile's K/Vt reads complete
        {
            const size_t kb = hb + (size_t)(t * 32 + kr) * DH + kc;
            *(ushort8*)&sKh[kr][kc] = *(const ushort8*)&Kh[kb];
            *(ushort8*)&sKl[kr][kc] = *(const ushort8*)&Kl[kb];
            const size_t vb = hb + (size_t)vr * SLEN + t * 32 + vc;
            *(ushort8*)&sVh[vr][vc] = *(const ushort8*)&Vth[vb];
            *(ushort8*)&sVl[vr][vc] = *(const ushort8*)&Vtl[vb];
        }
        __syncthreads();

        // S = Q K^T : per wave 16 q rows x 32 kv (2 col-frags)
        f32x4 s[2];
        s[0] = (f32x4)0.0f; s[1] = (f32x4)0.0f;
        #pragma unroll
        for (int j = 0; j < 2; ++j) {
            #pragma unroll
            for (int ks = 0; ks < 2; ++ks) {
                ushort8 kfh = *(const ushort8*)&sKh[j * 16 + fr][ks * 32 + kq];
                ushort8 kfl = *(const ushort8*)&sKl[j * 16 + fr][ks * 32 + kq];
                s[j] = mfma16(qh[ks], kfh, s[j]);
                s[j] = mfma16(qh[ks], kfl, s[j]);
                s[j] = mfma16(ql[ks], kfh, s[j]);
            }
        }

        // online softmax: lane's rows are g*4+r, cols j*16+fr
        float p[4][2];
        #pragma unroll
        for (int r = 0; r < 4; ++r) {
            const float v0 = s[0][r], v1 = s[1][r];
            float rm = fmaxf(v0, v1);
            #pragma unroll
            for (int off = 1; off < 16; off <<= 1)
                rm = fmaxf(rm, __shfl_xor(rm, off));
            const float mn   = fmaxf(mx[r], rm);
            const float corr = __expf(mx[r] - mn);
            mx[r] = mn;
            p[r][0] = __expf(v0 - mn);
            p[r][1] = __expf(v1 - mn);
            float rs = p[r][0] + p[r][1];
            #pragma unroll
            for (int off = 1; off < 16; off <<= 1)
                rs += __shfl_xor(rs, off);
            li[r] = li[r] * corr + rs;
            #pragma unroll
            for (int jd = 0; jd < 4; ++jd) acc[jd][r] *= corr;
        }

        // P -> wave-private LDS (in-wave DS ordering, no barrier needed)
        #pragma unroll
        for (int r = 0; r < 4; ++r)
            #pragma unroll
            for (int j = 0; j < 2; ++j)
                sP[wid][g * 4 + r][j * 16 + fr] = p[r][j];

        // O += P V : A = P[16q][32kv], B = Vt[d][kv]
        {
            float4 pa = *(const float4*)&sP[wid][fr][kq];
            float4 pb = *(const float4*)&sP[wid][fr][kq + 4];
            float pe[8] = {pa.x, pa.y, pa.z, pa.w, pb.x, pb.y, pb.z, pb.w};
            ushort8 ph, pl;
            #pragma unroll
            for (int e = 0; e < 8; ++e) {
                const unsigned short hh2 = f2bf(pe[e]);
                ph[e] = hh2;
                pl[e] = f2bf(pe[e] - bf2f(hh2));
            }
            #pragma unroll
            for (int jd = 0; jd < 4; ++jd) {
                ushort8 vfh = *(const ushort8*)&sVh[jd * 16 + fr][kq];
                ushort8 vfl = *(const ushort8*)&sVl[jd * 16 + fr][kq];
                acc[jd] = mfma16(ph, vfh, acc[jd]);
                acc[jd] = mfma16(ph, vfl, acc[jd]);
                acc[jd] = mfma16(pl, vfh, acc[jd]);
            }
        }
    }

    // epilogue: q = q0 + wid*16 + g*4 + r, d = jd*16 + fr; write hi/lo bf16
    #pragma unroll
    for (int r = 0; r < 4; ++r) {
        const float inv = 1.0f / li[r];
        const int q = q0 + wid * 16 + g * 4 + r;
        const size_t base = ((size_t)b * SLEN + q) * DM + h * DH;
        #pragma unroll
        for (int jd = 0; jd < 4; ++jd) {
            const float v = acc[jd][r] * inv;
            const unsigned short hh2 = f2bf(v);
            Ohi[base + jd * 16 + fr] = hh2;
            Olo[base + jd * 16 + fr] = f2bf(v - bf2f(hh2));
        }
    }
}

// ---------------------------------------------------------------------------
extern "C" void kernel_launch(void* const* d_in, const int* in_sizes, int n_in,
                              void* d_out, int out_size, void* d_ws, size_t ws_size,
                              hipStream_t stream)
{
    const float* x   = (const float*)d_in[0];
    const float* w_q = (const float*)d_in[1];
    const float* b_q = (const float*)d_in[2];
    const float* w_k = (const float*)d_in[3];
    const float* b_k = (const float*)d_in[4];
    const float* w_v = (const float*)d_in[5];
    const float* b_v = (const float*)d_in[6];
    const float* w_o = (const float*)d_in[7];
    const float* b_o = (const float*)d_in[8];
    float* out = (float*)d_out;

    // workspace (80 MB), all bf16:
    //   [0,8)   xh  (-> AO_hi after QKV)     [8,16)  xl (-> AO_lo)
    //   [16,24) wh[4]                        [24,32) wl[4]
    //   [32,40) Qh   [40,48) Ql   [48,56) Kh   [56,64) Kl
    //   [64,72) Vth  [72,80) Vtl
    char* w = (char*)d_ws;
    const size_t MB = 1024 * 1024;
    unsigned short* xh  = (unsigned short*)(w);
    unsigned short* xl  = (unsigned short*)(w + 8  * MB);
    unsigned short* wh  = (unsigned short*)(w + 16 * MB);
    unsigned short* wl  = (unsigned short*)(w + 24 * MB);
    unsigned short* Qh  = (unsigned short*)(w + 32 * MB);
    unsigned short* Ql  = (unsigned short*)(w + 40 * MB);
    unsigned short* Kh  = (unsigned short*)(w + 48 * MB);
    unsigned short* Kl  = (unsigned short*)(w + 56 * MB);
    unsigned short* Vth = (unsigned short*)(w + 64 * MB);
    unsigned short* Vtl = (unsigned short*)(w + 72 * MB);

    convert_hilo<<<8192, 256, 0, stream>>>(x, w_q, w_k, w_v, w_o, xh, xl, wh, wl);

    dim3 gg(2 * SLEN / 128, DM / 128);
    gemm_split<1><<<gg, 256, 0, stream>>>(xh, xl, wh + 0 * 1048576, wl + 0 * 1048576, b_q, 0.125f, nullptr, Qh, Ql);
    gemm_split<1><<<gg, 256, 0, stream>>>(xh, xl, wh + 1 * 1048576, wl + 1 * 1048576, b_k, 1.0f,   nullptr, Kh, Kl);
    gemm_split<2><<<gg, 256, 0, stream>>>(xh, xl, wh + 2 * 1048576, wl + 2 * 1048576, b_v, 1.0f,   nullptr, Vth, Vtl);

    dim3 ga(SLEN / 64, NH, 2);
    flash_attn_mfma<<<ga, 256, 0, stream>>>(Qh, Ql, Kh, Kl, Vth, Vtl, xh, xl);

    gemm_split<0><<<gg, 256, 0, stream>>>(xh, xl, wh + 3 * 1048576, wl + 3 * 1048576, b_o, 1.0f, out, nullptr, nullptr);
}